// Round 1
// baseline (215.812 us; speedup 1.0000x reference)
//
#include <hip/hip_runtime.h>
#include <cstdint>
#include <cstddef>

typedef __attribute__((ext_vector_type(8))) short bf16x8;
typedef __attribute__((ext_vector_type(4))) float f32x4;

#define S_    2048
#define D_    1024
#define F_    2048
#define O_    1024
#define E_    8
#define KCAP  256
#define ROWS  512           // 2 batches * KCAP per expert
#define NTOK  4096          // B*S

#define BM 128
#define BN 128
#define BK 64

// ---------- bf16 helpers (avoid __hip_bfloat16 ctor/union issues) ----------
__device__ __forceinline__ unsigned short f2bf(float f) {
  unsigned int u = __float_as_uint(f);
  u = (u + 0x7fffu + ((u >> 16) & 1u)) >> 16;   // RNE
  return (unsigned short)u;
}
__device__ __forceinline__ float bf2f(unsigned short h) {
  return __uint_as_float(((unsigned int)h) << 16);
}

// ---------- async global->LDS, 16B per lane, wave-uniform LDS base ----------
__device__ __forceinline__ void gload16(void* lds, const void* g) {
  auto gp = (__attribute__((address_space(1))) unsigned int*)(uintptr_t)g;
  // generic LDS pointer: low 32 bits are the LDS byte offset (aperture-high layout)
  auto lp = (__attribute__((address_space(3))) unsigned int*)(unsigned int)(uintptr_t)lds;
  __builtin_amdgcn_global_load_lds(gp, lp, 16, 0, 0);
}

// ---------- x fp32 -> bf16 ----------
__global__ void convert_x_kernel(const float* __restrict__ x, unsigned short* __restrict__ xb) {
  const int i = blockIdx.x * 256 + threadIdx.x;      // 0 .. NTOK*D_/8-1
  const float4* xi = (const float4*)x;
  float4 a = xi[(size_t)i * 2], b = xi[(size_t)i * 2 + 1];
  union { bf16x8 v; unsigned short u[8]; } u;
  u.u[0] = f2bf(a.x); u.u[1] = f2bf(a.y); u.u[2] = f2bf(a.z); u.u[3] = f2bf(a.w);
  u.u[4] = f2bf(b.x); u.u[5] = f2bf(b.y); u.u[6] = f2bf(b.z); u.u[7] = f2bf(b.w);
  *(bf16x8*)&xb[(size_t)i * 8] = u.v;
}

// ---------- per-expert transpose + fp32->bf16: out[C][R] = in[R][C] ----------
__global__ void transpose_cvt_kernel(const float* __restrict__ in, unsigned short* __restrict__ out,
                                     const int R, const int C) {
  __shared__ float t[64][65];
  const int e = blockIdx.z;
  const float* inp = in + (size_t)e * R * C;
  unsigned short* outp = out + (size_t)e * R * C;
  const int r0 = blockIdx.y * 64, c0 = blockIdx.x * 64;
  const int tid = threadIdx.x;
  const int lr = tid >> 4;          // 0..15
  const int lc = (tid & 15) * 4;    // 0..60
#pragma unroll
  for (int i = 0; i < 4; i++) {
    const int r = lr + i * 16;
    const float4 v = *(const float4*)&inp[(size_t)(r0 + r) * C + c0 + lc];
    t[r][lc] = v.x; t[r][lc + 1] = v.y; t[r][lc + 2] = v.z; t[r][lc + 3] = v.w;
  }
  __syncthreads();
#pragma unroll
  for (int i = 0; i < 4; i++) {
    const int oc = lr + i * 16;     // output row (a C-index)
    union { ushort4 u4; unsigned short u[4]; } u;
#pragma unroll
    for (int j = 0; j < 4; j++) u.u[j] = f2bf(t[lc + j][oc]);
    *(ushort4*)&outp[(size_t)(c0 + oc) * R + r0 + lc] = u.u4;
  }
}

// ---------- gating: logits (fp64 accum) + softmax probs ----------
__global__ void gating_kernel(const float* __restrict__ x, const float* __restrict__ wg,
                              float* __restrict__ logits, float* __restrict__ probs) {
  const int wave = threadIdx.x >> 6, lane = threadIdx.x & 63;
  const int t = blockIdx.x * 4 + wave;
  const float* xr = x + (size_t)t * D_;
  double acc[8] = {0, 0, 0, 0, 0, 0, 0, 0};
  const int d0 = lane * 16;
#pragma unroll
  for (int i = 0; i < 4; i++) {
    float4 xv = *(const float4*)&xr[d0 + i * 4];
    float xs[4] = {xv.x, xv.y, xv.z, xv.w};
#pragma unroll
    for (int j = 0; j < 4; j++) {
      const float4* wr = (const float4*)&wg[(size_t)(d0 + i * 4 + j) * 8];
      float4 w0 = wr[0], w1v = wr[1];
      double xd = (double)xs[j];
      acc[0] += xd * (double)w0.x;  acc[1] += xd * (double)w0.y;
      acc[2] += xd * (double)w0.z;  acc[3] += xd * (double)w0.w;
      acc[4] += xd * (double)w1v.x; acc[5] += xd * (double)w1v.y;
      acc[6] += xd * (double)w1v.z; acc[7] += xd * (double)w1v.w;
    }
  }
#pragma unroll
  for (int off = 32; off; off >>= 1) {
#pragma unroll
    for (int e = 0; e < 8; e++) acc[e] += __shfl_down(acc[e], off);
  }
  if (lane == 0) {
    double m = acc[0];
    for (int e = 1; e < 8; e++) m = acc[e] > m ? acc[e] : m;
    double p[8]; double s = 0;
    for (int e = 0; e < 8; e++) { p[e] = exp(acc[e] - m); s += p[e]; }
    const double inv = 1.0 / s;
    for (int e = 0; e < 8; e++) {
      logits[(size_t)t * 8 + e] = (float)acc[e];
      probs [(size_t)t * 8 + e] = (float)(p[e] * inv);
    }
  }
}

// ---------- expert-choice top-k via exact rank counting ----------
__global__ void topk_kernel(const float* __restrict__ logits, const float* __restrict__ probs,
                            int* __restrict__ sel, float* __restrict__ gate) {
  __shared__ float lv[S_];
  const int idx = blockIdx.x;       // 0..127 : (b,e) x 8 segments
  const int seg = idx & 7;
  const int be = idx >> 3;          // 0..15
  const int b = be >> 3;            // 0..1
  const int e = be & 7;
  const int tid = threadIdx.x;
  for (int i = tid; i < S_; i += 256)
    lv[i] = logits[((size_t)(b * S_ + i)) * E_ + e];
  __syncthreads();
  const int s = seg * 256 + tid;
  const float v = lv[s];
  int rank = 0;
#pragma unroll 8
  for (int i = 0; i < S_; i++) {
    float u = lv[i];
    rank += (u > v) || (u == v && i < s);     // lax.top_k tie-break: lower index first
  }
  if (rank < KCAP) {
    sel [e * ROWS + b * KCAP + rank] = b * S_ + s;
    gate[e * ROWS + b * KCAP + rank] = probs[((size_t)(b * S_ + s)) * E_ + e];
  }
}

// ---------- GEMM1: h[e][row][f] = gelu(x_gather . w1[e] + b1[e]) ----------
__global__ __launch_bounds__(256, 2) void gemm1_kernel(
    const unsigned short* __restrict__ xb,   // [NTOK][D_]
    const unsigned short* __restrict__ w1t,  // [E][F_][D_]
    const float* __restrict__ b1,            // [E][F_]
    const int* __restrict__ sel,             // [E][ROWS]
    unsigned short* __restrict__ hbuf) {     // [E][ROWS][F_]
  __shared__ unsigned short As[BM * BK];
  __shared__ unsigned short Bs[BN * BK];
  const int e = blockIdx.z;
  const int m0 = blockIdx.y * BM;
  const int n0 = blockIdx.x * BN;
  const int tid = threadIdx.x;
  const int wave = tid >> 6, lane = tid & 63;
  const int wr = wave >> 1, wc = wave & 1;

  const unsigned short* asrc[4];
  const unsigned short* bsrc[4];
#pragma unroll
  for (int j = 0; j < 4; j++) {
    const int r = wave * 32 + j * 8 + (lane >> 3);
    const int tok = sel[e * ROWS + m0 + r];
    asrc[j] = xb + (size_t)tok * D_ + (lane & 7) * 8;
    bsrc[j] = w1t + ((size_t)e * F_ + n0 + r) * D_ + (lane & 7) * 8;
  }
  f32x4 acc[4][4];
#pragma unroll
  for (int mi = 0; mi < 4; mi++)
#pragma unroll
    for (int nj = 0; nj < 4; nj++) acc[mi][nj] = (f32x4){0.f, 0.f, 0.f, 0.f};

  for (int k0 = 0; k0 < D_; k0 += BK) {
    __syncthreads();
#pragma unroll
    for (int j = 0; j < 4; j++) {
      gload16(&As[(wave * 32 + j * 8) * BK], asrc[j] + k0);
      gload16(&Bs[(wave * 32 + j * 8) * BK], bsrc[j] + k0);
    }
    __syncthreads();
    bf16x8 af[2][4], bfv[2][4];
    const int arow = wr * 64 + (lane & 15);
    const int brow = wc * 64 + (lane & 15);
    const int kc = (lane >> 4) * 8;
#pragma unroll
    for (int kk = 0; kk < 2; kk++) {
#pragma unroll
      for (int mi = 0; mi < 4; mi++)
        af[kk][mi] = *(const bf16x8*)&As[(arow + mi * 16) * BK + kk * 32 + kc];
#pragma unroll
      for (int nj = 0; nj < 4; nj++)
        bfv[kk][nj] = *(const bf16x8*)&Bs[(brow + nj * 16) * BK + kk * 32 + kc];
    }
#pragma unroll
    for (int kk = 0; kk < 2; kk++)
#pragma unroll
      for (int mi = 0; mi < 4; mi++)
#pragma unroll
        for (int nj = 0; nj < 4; nj++)
          acc[mi][nj] = __builtin_amdgcn_mfma_f32_16x16x32_bf16(af[kk][mi], bfv[kk][nj], acc[mi][nj], 0, 0, 0);
  }
  const int lr = (lane >> 4) * 4;
  const int lc = lane & 15;
#pragma unroll
  for (int mi = 0; mi < 4; mi++)
#pragma unroll
    for (int nj = 0; nj < 4; nj++)
#pragma unroll
      for (int rg = 0; rg < 4; rg++) {
        const int row = m0 + wr * 64 + mi * 16 + lr + rg;
        const int col = n0 + wc * 64 + nj * 16 + lc;
        float v = acc[mi][nj][rg] + b1[e * F_ + col];
        v = 0.5f * v * (1.0f + erff(v * 0.70710678118654752f));   // exact GELU
        hbuf[((size_t)e * ROWS + row) * F_ + col] = f2bf(v);
      }
}

// ---------- row LayerNorm over F_, in place on bf16 h ----------
__global__ void ln_kernel(unsigned short* __restrict__ hbuf,
                          const float* __restrict__ g_ln, const float* __restrict__ b_ln) {
  const int row = blockIdx.x;          // 0..E_*ROWS-1
  const int e = row >> 9;
  unsigned short* hr = hbuf + (size_t)row * F_;
  const int tid = threadIdx.x;
  union { bf16x8 v; unsigned short u[8]; } u;
  u.v = *(const bf16x8*)&hr[tid * 8];
  float vals[8]; float s1 = 0.f, s2 = 0.f;
#pragma unroll
  for (int j = 0; j < 8; j++) { float f = bf2f(u.u[j]); vals[j] = f; s1 += f; s2 += f * f; }
#pragma unroll
  for (int off = 32; off; off >>= 1) { s1 += __shfl_down(s1, off); s2 += __shfl_down(s2, off); }
  __shared__ float rs[8];
  const int wave = tid >> 6, lane = tid & 63;
  if (lane == 0) { rs[wave] = s1; rs[wave + 4] = s2; }
  __syncthreads();
  const float t1 = rs[0] + rs[1] + rs[2] + rs[3];
  const float t2 = rs[4] + rs[5] + rs[6] + rs[7];
  const float mu = t1 * (1.f / F_);
  const float var = t2 * (1.f / F_) - mu * mu;   // biased var (jnp.var)
  const float rstd = rsqrtf(var + 1e-5f);
  const float* gl = g_ln + (size_t)e * F_;
  const float* bl = b_ln + (size_t)e * F_;
  union { bf16x8 v; unsigned short u[8]; } o;
#pragma unroll
  for (int j = 0; j < 8; j++) {
    const int f = tid * 8 + j;
    o.u[j] = f2bf((vals[j] - mu) * rstd * gl[f] + bl[f]);
  }
  *(bf16x8*)&hr[tid * 8] = o.v;
}

// ---------- GEMM2: out[tok] += gate * (h . w2[e] + b2[e]) ----------
__global__ __launch_bounds__(256, 2) void gemm2_kernel(
    const unsigned short* __restrict__ hbuf, // [E][ROWS][F_]
    const unsigned short* __restrict__ w2t,  // [E][O_][F_]
    const float* __restrict__ b2,            // [E][O_]
    const int* __restrict__ sel, const float* __restrict__ gate,
    float* __restrict__ out) {               // [NTOK][O_]
  __shared__ unsigned short As[BM * BK];
  __shared__ unsigned short Bs[BN * BK];
  const int e = blockIdx.z;
  const int m0 = blockIdx.y * BM;
  const int n0 = blockIdx.x * BN;
  const int tid = threadIdx.x;
  const int wave = tid >> 6, lane = tid & 63;
  const int wr = wave >> 1, wc = wave & 1;

  const unsigned short* asrc[4];
  const unsigned short* bsrc[4];
#pragma unroll
  for (int j = 0; j < 4; j++) {
    const int r = wave * 32 + j * 8 + (lane >> 3);
    asrc[j] = hbuf + ((size_t)e * ROWS + m0 + r) * F_ + (lane & 7) * 8;
    bsrc[j] = w2t + ((size_t)e * O_ + n0 + r) * F_ + (lane & 7) * 8;
  }
  f32x4 acc[4][4];
#pragma unroll
  for (int mi = 0; mi < 4; mi++)
#pragma unroll
    for (int nj = 0; nj < 4; nj++) acc[mi][nj] = (f32x4){0.f, 0.f, 0.f, 0.f};

  for (int k0 = 0; k0 < F_; k0 += BK) {
    __syncthreads();
#pragma unroll
    for (int j = 0; j < 4; j++) {
      gload16(&As[(wave * 32 + j * 8) * BK], asrc[j] + k0);
      gload16(&Bs[(wave * 32 + j * 8) * BK], bsrc[j] + k0);
    }
    __syncthreads();
    bf16x8 af[2][4], bfv[2][4];
    const int arow = wr * 64 + (lane & 15);
    const int brow = wc * 64 + (lane & 15);
    const int kc = (lane >> 4) * 8;
#pragma unroll
    for (int kk = 0; kk < 2; kk++) {
#pragma unroll
      for (int mi = 0; mi < 4; mi++)
        af[kk][mi] = *(const bf16x8*)&As[(arow + mi * 16) * BK + kk * 32 + kc];
#pragma unroll
      for (int nj = 0; nj < 4; nj++)
        bfv[kk][nj] = *(const bf16x8*)&Bs[(brow + nj * 16) * BK + kk * 32 + kc];
    }
#pragma unroll
    for (int kk = 0; kk < 2; kk++)
#pragma unroll
      for (int mi = 0; mi < 4; mi++)
#pragma unroll
        for (int nj = 0; nj < 4; nj++)
          acc[mi][nj] = __builtin_amdgcn_mfma_f32_16x16x32_bf16(af[kk][mi], bfv[kk][nj], acc[mi][nj], 0, 0, 0);
  }
  const int lr = (lane >> 4) * 4;
  const int lc = lane & 15;
#pragma unroll
  for (int mi = 0; mi < 4; mi++) {
#pragma unroll
    for (int rg = 0; rg < 4; rg++) {
      const int row = m0 + wr * 64 + mi * 16 + lr + rg;
      const int tok = sel[e * ROWS + row];
      const float g = gate[e * ROWS + row];
#pragma unroll
      for (int nj = 0; nj < 4; nj++) {
        const int col = n0 + wc * 64 + nj * 16 + lc;
        const float v = acc[mi][nj][rg] + b2[e * O_ + col];
        atomicAdd(&out[(size_t)tok * O_ + col], g * v);
      }
    }
  }
}

// ---------- launch ----------
extern "C" void kernel_launch(void* const* d_in, const int* in_sizes, int n_in,
                              void* d_out, int out_size, void* d_ws, size_t ws_size,
                              hipStream_t stream) {
  const float* x     = (const float*)d_in[0];
  const float* wg    = (const float*)d_in[1];
  const float* w1    = (const float*)d_in[2];
  const float* b1    = (const float*)d_in[3];
  const float* g_ln  = (const float*)d_in[4];
  const float* b_ln  = (const float*)d_in[5];
  const float* w2    = (const float*)d_in[6];
  const float* b2    = (const float*)d_in[7];
  float* out = (float*)d_out;
  float* out_logits = out + (size_t)NTOK * O_;

  char* wsb = (char*)d_ws;
  unsigned short* xb   = (unsigned short*)(wsb + 0);          // 8,388,608 B
  unsigned short* w1t  = (unsigned short*)(wsb + 8388608);    // 33,554,432 B
  unsigned short* w2t  = (unsigned short*)(wsb + 41943040);   // 33,554,432 B
  unsigned short* hbuf = (unsigned short*)(wsb + 75497472);   // 16,777,216 B
  float* probs = (float*)(wsb + 92274688);                    // 131,072 B
  int*   sel   = (int*)  (wsb + 92405760);                    // 16,384 B
  float* gate  = (float*)(wsb + 92422144);                    // 16,384 B

  // zero the moe-output region (atomic accumulation target)
  hipMemsetAsync(d_out, 0, (size_t)NTOK * O_ * sizeof(float), stream);

  convert_x_kernel<<<NTOK * D_ / 8 / 256, 256, 0, stream>>>(x, xb);
  transpose_cvt_kernel<<<dim3(F_ / 64, D_ / 64, E_), 256, 0, stream>>>(w1, w1t, D_, F_); // -> [F][D]
  transpose_cvt_kernel<<<dim3(O_ / 64, F_ / 64, E_), 256, 0, stream>>>(w2, w2t, F_, O_); // -> [O][F]
  gating_kernel<<<NTOK / 4, 256, 0, stream>>>(x, wg, out_logits, probs);
  topk_kernel<<<2 * E_ * 8, 256, 0, stream>>>(out_logits, probs, sel, gate);
  gemm1_kernel<<<dim3(F_ / BN, ROWS / BM, E_), 256, 0, stream>>>(xb, w1t, b1, sel, hbuf);
  ln_kernel<<<E_ * ROWS, 256, 0, stream>>>(hbuf, g_ln, b_ln);
  gemm2_kernel<<<dim3(O_ / BN, ROWS / BM, E_), 256, 0, stream>>>(hbuf, w2t, b2, sel, gate, out);
}

// Round 2
// 190.644 us; speedup vs baseline: 1.1320x; 1.1320x over previous
//
#include <hip/hip_runtime.h>
#include <cstdint>
#include <cstddef>

typedef __attribute__((ext_vector_type(8))) short bf16x8;
typedef __attribute__((ext_vector_type(4))) float f32x4;

#define S_    2048
#define D_    1024
#define F_    2048
#define O_    1024
#define E_    8
#define KCAP  256
#define ROWS  512           // 2 batches * KCAP per expert
#define NTOK  4096          // B*S

#define BM 64
#define BN 64
#define BK 64
#define TILE_ELEMS (BM * BK)   // 4096 ushorts per buffer per matrix

// ---------- bf16 helpers ----------
__device__ __forceinline__ unsigned short f2bf(float f) {
  unsigned int u = __float_as_uint(f);
  u = (u + 0x7fffu + ((u >> 16) & 1u)) >> 16;   // RNE
  return (unsigned short)u;
}
__device__ __forceinline__ float bf2f(unsigned short h) {
  return __uint_as_float(((unsigned int)h) << 16);
}

// ---------- async global->LDS, 16B per lane, wave-uniform LDS base ----------
__device__ __forceinline__ void gload16(void* lds, const void* g) {
  auto gp = (__attribute__((address_space(1))) unsigned int*)(uintptr_t)g;
  auto lp = (__attribute__((address_space(3))) unsigned int*)(unsigned int)(uintptr_t)lds;
  __builtin_amdgcn_global_load_lds(gp, lp, 16, 0, 0);
}

// ---------- gating: logits (fp64 accum) + softmax probs + x->bf16 ----------
__global__ void gating_kernel(const float* __restrict__ x, const float* __restrict__ wg,
                              float* __restrict__ logits, float* __restrict__ probs,
                              unsigned short* __restrict__ xb) {
  const int wave = threadIdx.x >> 6, lane = threadIdx.x & 63;
  const int t = blockIdx.x * 4 + wave;
  const float* xr = x + (size_t)t * D_;
  double acc[8] = {0, 0, 0, 0, 0, 0, 0, 0};
  const int d0 = lane * 16;
#pragma unroll
  for (int i = 0; i < 4; i++) {
    float4 xv = *(const float4*)&xr[d0 + i * 4];
    // fused fp32->bf16 conversion of x
    union { ushort4 u4; unsigned short u[4]; } cv;
    cv.u[0] = f2bf(xv.x); cv.u[1] = f2bf(xv.y); cv.u[2] = f2bf(xv.z); cv.u[3] = f2bf(xv.w);
    *(ushort4*)&xb[(size_t)t * D_ + d0 + i * 4] = cv.u4;
    float xs[4] = {xv.x, xv.y, xv.z, xv.w};
#pragma unroll
    for (int j = 0; j < 4; j++) {
      const float4* wr = (const float4*)&wg[(size_t)(d0 + i * 4 + j) * 8];
      float4 w0 = wr[0], w1v = wr[1];
      double xd = (double)xs[j];
      acc[0] += xd * (double)w0.x;  acc[1] += xd * (double)w0.y;
      acc[2] += xd * (double)w0.z;  acc[3] += xd * (double)w0.w;
      acc[4] += xd * (double)w1v.x; acc[5] += xd * (double)w1v.y;
      acc[6] += xd * (double)w1v.z; acc[7] += xd * (double)w1v.w;
    }
  }
#pragma unroll
  for (int off = 32; off; off >>= 1) {
#pragma unroll
    for (int e = 0; e < 8; e++) acc[e] += __shfl_down(acc[e], off);
  }
  if (lane == 0) {
    double m = acc[0];
    for (int e = 1; e < 8; e++) m = acc[e] > m ? acc[e] : m;
    double p[8]; double s = 0;
    for (int e = 0; e < 8; e++) { p[e] = exp(acc[e] - m); s += p[e]; }
    const double inv = 1.0 / s;
    for (int e = 0; e < 8; e++) {
      logits[(size_t)t * 8 + e] = (float)acc[e];
      probs [(size_t)t * 8 + e] = (float)(p[e] * inv);
    }
  }
}

// ---------- per-expert transpose + fp32->bf16: out[C][R] = in[R][C] ----------
__global__ void transpose_cvt_kernel(const float* __restrict__ in, unsigned short* __restrict__ out,
                                     const int R, const int C) {
  __shared__ float t[64][65];
  const int e = blockIdx.z;
  const float* inp = in + (size_t)e * R * C;
  unsigned short* outp = out + (size_t)e * R * C;
  const int r0 = blockIdx.y * 64, c0 = blockIdx.x * 64;
  const int tid = threadIdx.x;
  const int lr = tid >> 4;          // 0..15
  const int lc = (tid & 15) * 4;    // 0..60
#pragma unroll
  for (int i = 0; i < 4; i++) {
    const int r = lr + i * 16;
    const float4 v = *(const float4*)&inp[(size_t)(r0 + r) * C + c0 + lc];
    t[r][lc] = v.x; t[r][lc + 1] = v.y; t[r][lc + 2] = v.z; t[r][lc + 3] = v.w;
  }
  __syncthreads();
#pragma unroll
  for (int i = 0; i < 4; i++) {
    const int oc = lr + i * 16;     // output row (a C-index)
    union { ushort4 u4; unsigned short u[4]; } u;
#pragma unroll
    for (int j = 0; j < 4; j++) u.u[j] = f2bf(t[lc + j][oc]);
    *(ushort4*)&outp[(size_t)(c0 + oc) * R + r0 + lc] = u.u4;
  }
}

// ---------- expert-choice top-k via exact rank counting ----------
__global__ void topk_kernel(const float* __restrict__ logits, const float* __restrict__ probs,
                            int* __restrict__ sel, float* __restrict__ gate) {
  __shared__ float lv[S_];
  const int idx = blockIdx.x;       // 0..127 : (b,e) x 8 segments
  const int seg = idx & 7;
  const int be = idx >> 3;          // 0..15
  const int b = be >> 3;            // 0..1
  const int e = be & 7;
  const int tid = threadIdx.x;
  for (int i = tid; i < S_; i += 256)
    lv[i] = logits[((size_t)(b * S_ + i)) * E_ + e];
  __syncthreads();
  const int s = seg * 256 + tid;
  const float v = lv[s];
  int rank = 0;
#pragma unroll 8
  for (int i = 0; i < S_; i++) {
    float u = lv[i];
    rank += (u > v) || (u == v && i < s);     // lax.top_k tie-break: lower index first
  }
  if (rank < KCAP) {
    sel [e * ROWS + b * KCAP + rank] = b * S_ + s;
    gate[e * ROWS + b * KCAP + rank] = probs[((size_t)(b * S_ + s)) * E_ + e];
  }
}

// ====================== GEMM1: h = gelu(gather(x) . w1^T + b1) ======================
// 64x64x64 tiles, 2-phase dbuf prefetch, XOR-swizzled LDS, expert-per-XCD mapping.
__global__ __launch_bounds__(256, 4) void gemm1_kernel(
    const unsigned short* __restrict__ xb,   // [NTOK][D_]
    const unsigned short* __restrict__ w1t,  // [E][F_][D_]
    const float* __restrict__ b1,            // [E][F_]
    const int* __restrict__ sel,             // [E][ROWS]
    unsigned short* __restrict__ hbuf) {     // [E][ROWS][F_]
  __shared__ unsigned short As[2 * TILE_ELEMS];
  __shared__ unsigned short Bs[2 * TILE_ELEMS];
  // bijective XCD chunking: 2048 blocks = 8 XCDs x 256; XCD x owns expert x
  const int bid = blockIdx.x;
  const int lid = (bid & 7) * 256 + (bid >> 3);
  const int e   = lid >> 8;           // 0..7
  const int rem = lid & 255;
  const int n0  = (rem >> 3) * BN;    // 0..31 -> F panels
  const int m0  = (rem & 7) * BM;     // 0..7  -> row panels
  const int tid = threadIdx.x;
  const int wave = tid >> 6, lane = tid & 63;
  const int wr = wave >> 1, wc = wave & 1;

  // staging: per gload16 a wave covers 8 rows x 8 chunks of 16B.
  // LDS(r, c) = Global(r, c ^ (r&7))  -> pre-swizzle SOURCE chunk (rule 21).
  const int srow = lane >> 3;                 // 0..7 == r&7 (rowbase % 8 == 0)
  const int schunk = (lane & 7) ^ srow;
  const unsigned short* asrc[2];
  const unsigned short* bsrc[2];
#pragma unroll
  for (int j = 0; j < 2; j++) {
    const int r = wave * 16 + j * 8 + srow;
    const int tok = sel[e * ROWS + m0 + r];
    asrc[j] = xb + (size_t)tok * D_ + schunk * 8;
    bsrc[j] = w1t + ((size_t)e * F_ + n0 + r) * D_ + schunk * 8;
  }

  f32x4 acc[2][2];
#pragma unroll
  for (int mi = 0; mi < 2; mi++)
#pragma unroll
    for (int nj = 0; nj < 2; nj++) acc[mi][nj] = (f32x4){0.f, 0.f, 0.f, 0.f};

  const int fr = lane & 15;

  auto stage = [&](int buf, int k0) {
#pragma unroll
    for (int j = 0; j < 2; j++) {
      gload16(&As[buf * TILE_ELEMS + (wave * 16 + j * 8) * BK], asrc[j] + k0);
      gload16(&Bs[buf * TILE_ELEMS + (wave * 16 + j * 8) * BK], bsrc[j] + k0);
    }
  };
  auto compute = [&](int buf) {
    const unsigned short* Ab = &As[buf * TILE_ELEMS];
    const unsigned short* Bb = &Bs[buf * TILE_ELEMS];
    bf16x8 a[2][2], b[2][2];
#pragma unroll
    for (int kk = 0; kk < 2; kk++) {
      const int xch = ((kk * 4 + (lane >> 4)) ^ (lane & 7)) * 8;  // swizzled read chunk
#pragma unroll
      for (int mi = 0; mi < 2; mi++)
        a[kk][mi] = *(const bf16x8*)&Ab[(wr * 32 + mi * 16 + fr) * BK + xch];
#pragma unroll
      for (int nj = 0; nj < 2; nj++)
        b[kk][nj] = *(const bf16x8*)&Bb[(wc * 32 + nj * 16 + fr) * BK + xch];
    }
#pragma unroll
    for (int kk = 0; kk < 2; kk++)
#pragma unroll
      for (int mi = 0; mi < 2; mi++)
#pragma unroll
        for (int nj = 0; nj < 2; nj++)
          acc[mi][nj] = __builtin_amdgcn_mfma_f32_16x16x32_bf16(a[kk][mi], b[kk][nj], acc[mi][nj], 0, 0, 0);
  };

  stage(0, 0);
  __syncthreads();
  int cur = 0;
  for (int t = 0; t < D_ / BK - 1; t++) {
    stage(cur ^ 1, (t + 1) * BK);     // prefetch next tile, in flight under compute
    compute(cur);
    __syncthreads();                  // drains vmcnt(0): next tile ready
    cur ^= 1;
  }
  compute(cur);

  const int lr = (lane >> 4) * 4;
#pragma unroll
  for (int mi = 0; mi < 2; mi++)
#pragma unroll
    for (int nj = 0; nj < 2; nj++)
#pragma unroll
      for (int rg = 0; rg < 4; rg++) {
        const int row = m0 + wr * 32 + mi * 16 + lr + rg;
        const int col = n0 + wc * 32 + nj * 16 + fr;
        float v = acc[mi][nj][rg] + b1[e * F_ + col];
        v = 0.5f * v * (1.0f + erff(v * 0.70710678118654752f));   // exact GELU
        hbuf[((size_t)e * ROWS + row) * F_ + col] = f2bf(v);
      }
}

// ---------- row LayerNorm over F_, in place on bf16 h ----------
__global__ void ln_kernel(unsigned short* __restrict__ hbuf,
                          const float* __restrict__ g_ln, const float* __restrict__ b_ln) {
  const int row = blockIdx.x;          // 0..E_*ROWS-1
  const int e = row >> 9;
  unsigned short* hr = hbuf + (size_t)row * F_;
  const int tid = threadIdx.x;
  union { bf16x8 v; unsigned short u[8]; } u;
  u.v = *(const bf16x8*)&hr[tid * 8];
  float vals[8]; float s1 = 0.f, s2 = 0.f;
#pragma unroll
  for (int j = 0; j < 8; j++) { float f = bf2f(u.u[j]); vals[j] = f; s1 += f; s2 += f * f; }
#pragma unroll
  for (int off = 32; off; off >>= 1) { s1 += __shfl_down(s1, off); s2 += __shfl_down(s2, off); }
  __shared__ float rs[8];
  const int wave = tid >> 6, lane = tid & 63;
  if (lane == 0) { rs[wave] = s1; rs[wave + 4] = s2; }
  __syncthreads();
  const float t1 = rs[0] + rs[1] + rs[2] + rs[3];
  const float t2 = rs[4] + rs[5] + rs[6] + rs[7];
  const float mu = t1 * (1.f / F_);
  const float var = t2 * (1.f / F_) - mu * mu;   // biased var (jnp.var)
  const float rstd = rsqrtf(var + 1e-5f);
  const float4* gl4 = (const float4*)(g_ln + (size_t)e * F_ + tid * 8);
  const float4* bl4 = (const float4*)(b_ln + (size_t)e * F_ + tid * 8);
  float4 g0 = gl4[0], g1 = gl4[1], bb0 = bl4[0], bb1 = bl4[1];
  float gs[8] = {g0.x, g0.y, g0.z, g0.w, g1.x, g1.y, g1.z, g1.w};
  float bs[8] = {bb0.x, bb0.y, bb0.z, bb0.w, bb1.x, bb1.y, bb1.z, bb1.w};
  union { bf16x8 v; unsigned short u[8]; } o;
#pragma unroll
  for (int j = 0; j < 8; j++)
    o.u[j] = f2bf((vals[j] - mu) * rstd * gs[j] + bs[j]);
  *(bf16x8*)&hr[tid * 8] = o.v;
}

// ====================== GEMM2: out[tok] += gate * (h . w2^T + b2) ======================
__global__ __launch_bounds__(256, 4) void gemm2_kernel(
    const unsigned short* __restrict__ hbuf, // [E][ROWS][F_]
    const unsigned short* __restrict__ w2t,  // [E][O_][F_]
    const float* __restrict__ b2,            // [E][O_]
    const int* __restrict__ sel, const float* __restrict__ gate,
    float* __restrict__ out) {               // [NTOK][O_]
  __shared__ unsigned short As[2 * TILE_ELEMS];
  __shared__ unsigned short Bs[2 * TILE_ELEMS];
  // 1024 blocks = 8 XCDs x 128; XCD x owns expert x
  const int bid = blockIdx.x;
  const int lid = (bid & 7) * 128 + (bid >> 3);
  const int e   = lid >> 7;           // 0..7
  const int rem = lid & 127;
  const int n0  = (rem >> 3) * BN;    // 0..15 -> O panels
  const int m0  = (rem & 7) * BM;     // 0..7
  const int tid = threadIdx.x;
  const int wave = tid >> 6, lane = tid & 63;
  const int wr = wave >> 1, wc = wave & 1;

  const int srow = lane >> 3;
  const int schunk = (lane & 7) ^ srow;
  const unsigned short* asrc[2];
  const unsigned short* bsrc[2];
#pragma unroll
  for (int j = 0; j < 2; j++) {
    const int r = wave * 16 + j * 8 + srow;
    asrc[j] = hbuf + ((size_t)e * ROWS + m0 + r) * F_ + schunk * 8;
    bsrc[j] = w2t + ((size_t)e * O_ + n0 + r) * F_ + schunk * 8;
  }

  f32x4 acc[2][2];
#pragma unroll
  for (int mi = 0; mi < 2; mi++)
#pragma unroll
    for (int nj = 0; nj < 2; nj++) acc[mi][nj] = (f32x4){0.f, 0.f, 0.f, 0.f};

  const int fr = lane & 15;

  auto stage = [&](int buf, int k0) {
#pragma unroll
    for (int j = 0; j < 2; j++) {
      gload16(&As[buf * TILE_ELEMS + (wave * 16 + j * 8) * BK], asrc[j] + k0);
      gload16(&Bs[buf * TILE_ELEMS + (wave * 16 + j * 8) * BK], bsrc[j] + k0);
    }
  };
  auto compute = [&](int buf) {
    const unsigned short* Ab = &As[buf * TILE_ELEMS];
    const unsigned short* Bb = &Bs[buf * TILE_ELEMS];
    bf16x8 a[2][2], b[2][2];
#pragma unroll
    for (int kk = 0; kk < 2; kk++) {
      const int xch = ((kk * 4 + (lane >> 4)) ^ (lane & 7)) * 8;
#pragma unroll
      for (int mi = 0; mi < 2; mi++)
        a[kk][mi] = *(const bf16x8*)&Ab[(wr * 32 + mi * 16 + fr) * BK + xch];
#pragma unroll
      for (int nj = 0; nj < 2; nj++)
        b[kk][nj] = *(const bf16x8*)&Bb[(wc * 32 + nj * 16 + fr) * BK + xch];
    }
#pragma unroll
    for (int kk = 0; kk < 2; kk++)
#pragma unroll
      for (int mi = 0; mi < 2; mi++)
#pragma unroll
        for (int nj = 0; nj < 2; nj++)
          acc[mi][nj] = __builtin_amdgcn_mfma_f32_16x16x32_bf16(a[kk][mi], b[kk][nj], acc[mi][nj], 0, 0, 0);
  };

  stage(0, 0);
  __syncthreads();
  int cur = 0;
  for (int t = 0; t < F_ / BK - 1; t++) {
    stage(cur ^ 1, (t + 1) * BK);
    compute(cur);
    __syncthreads();
    cur ^= 1;
  }
  compute(cur);

  const int lr = (lane >> 4) * 4;
#pragma unroll
  for (int mi = 0; mi < 2; mi++) {
#pragma unroll
    for (int rg = 0; rg < 4; rg++) {
      const int row = m0 + wr * 32 + mi * 16 + lr + rg;
      const int tok = sel[e * ROWS + row];
      const float g = gate[e * ROWS + row];
#pragma unroll
      for (int nj = 0; nj < 2; nj++) {
        const int col = n0 + wc * 32 + nj * 16 + fr;
        const float v = acc[mi][nj][rg] + b2[e * O_ + col];
        atomicAdd(&out[(size_t)tok * O_ + col], g * v);
      }
    }
  }
}

// ---------- launch ----------
extern "C" void kernel_launch(void* const* d_in, const int* in_sizes, int n_in,
                              void* d_out, int out_size, void* d_ws, size_t ws_size,
                              hipStream_t stream) {
  const float* x     = (const float*)d_in[0];
  const float* wg    = (const float*)d_in[1];
  const float* w1    = (const float*)d_in[2];
  const float* b1    = (const float*)d_in[3];
  const float* g_ln  = (const float*)d_in[4];
  const float* b_ln  = (const float*)d_in[5];
  const float* w2    = (const float*)d_in[6];
  const float* b2    = (const float*)d_in[7];
  float* out = (float*)d_out;
  float* out_logits = out + (size_t)NTOK * O_;

  char* wsb = (char*)d_ws;
  unsigned short* xb   = (unsigned short*)(wsb + 0);          // 8,388,608 B
  unsigned short* w1t  = (unsigned short*)(wsb + 8388608);    // 33,554,432 B
  unsigned short* w2t  = (unsigned short*)(wsb + 41943040);   // 33,554,432 B
  unsigned short* hbuf = (unsigned short*)(wsb + 75497472);   // 16,777,216 B
  float* probs = (float*)(wsb + 92274688);                    // 131,072 B
  int*   sel   = (int*)  (wsb + 92405760);                    // 16,384 B
  float* gate  = (float*)(wsb + 92422144);                    // 16,384 B

  // zero the moe-output region (atomic accumulation target)
  hipMemsetAsync(d_out, 0, (size_t)NTOK * O_ * sizeof(float), stream);

  gating_kernel<<<NTOK / 4, 256, 0, stream>>>(x, wg, out_logits, probs, xb);
  transpose_cvt_kernel<<<dim3(F_ / 64, D_ / 64, E_), 256, 0, stream>>>(w1, w1t, D_, F_); // -> [F][D]
  transpose_cvt_kernel<<<dim3(O_ / 64, F_ / 64, E_), 256, 0, stream>>>(w2, w2t, F_, O_); // -> [O][F]
  topk_kernel<<<2 * E_ * 8, 256, 0, stream>>>(out_logits, probs, sel, gate);
  gemm1_kernel<<<(F_ / BN) * (ROWS / BM) * E_, 256, 0, stream>>>(xb, w1t, b1, sel, hbuf);
  ln_kernel<<<E_ * ROWS, 256, 0, stream>>>(hbuf, g_ln, b_ln);
  gemm2_kernel<<<(O_ / BN) * (ROWS / BM) * E_, 256, 0, stream>>>(hbuf, w2t, b2, sel, gate, out);
}

// Round 3
// 156.642 us; speedup vs baseline: 1.3777x; 1.2171x over previous
//
#include <hip/hip_runtime.h>
#include <cstdint>
#include <cstddef>

typedef __attribute__((ext_vector_type(8))) short bf16x8;
typedef __attribute__((ext_vector_type(4))) float f32x4;

#define S_    2048
#define D_    1024
#define F_    2048
#define O_    1024
#define E_    8
#define KCAP  256
#define ROWS  512           // 2 batches * KCAP per expert
#define NTOK  4096          // B*S

#define BM 64
#define BN 64
#define BK 64
#define TILE_ELEMS (BM * BK)   // 4096 ushorts per buffer per matrix

// ---------- bf16 helpers ----------
__device__ __forceinline__ unsigned short f2bf(float f) {
  unsigned int u = __float_as_uint(f);
  u = (u + 0x7fffu + ((u >> 16) & 1u)) >> 16;   // RNE
  return (unsigned short)u;
}
__device__ __forceinline__ float bf2f(unsigned short h) {
  return __uint_as_float(((unsigned int)h) << 16);
}

// ---------- async global->LDS, 16B per lane, wave-uniform LDS base ----------
__device__ __forceinline__ void gload16(void* lds, const void* g) {
  auto gp = (__attribute__((address_space(1))) unsigned int*)(uintptr_t)g;
  auto lp = (__attribute__((address_space(3))) unsigned int*)(unsigned int)(uintptr_t)lds;
  __builtin_amdgcn_global_load_lds(gp, lp, 16, 0, 0);
}

// ---------- gating: logits (fp64 accum) + softmax probs + x->bf16 ----------
__global__ void gating_kernel(const float* __restrict__ x, const float* __restrict__ wg,
                              float* __restrict__ logits, float* __restrict__ probs,
                              unsigned short* __restrict__ xb) {
  const int wave = threadIdx.x >> 6, lane = threadIdx.x & 63;
  const int t = blockIdx.x * 4 + wave;
  const float* xr = x + (size_t)t * D_;
  double acc[8] = {0, 0, 0, 0, 0, 0, 0, 0};
  const int d0 = lane * 16;
#pragma unroll
  for (int i = 0; i < 4; i++) {
    float4 xv = *(const float4*)&xr[d0 + i * 4];
    // fused fp32->bf16 conversion of x
    union { ushort4 u4; unsigned short u[4]; } cv;
    cv.u[0] = f2bf(xv.x); cv.u[1] = f2bf(xv.y); cv.u[2] = f2bf(xv.z); cv.u[3] = f2bf(xv.w);
    *(ushort4*)&xb[(size_t)t * D_ + d0 + i * 4] = cv.u4;
    float xs[4] = {xv.x, xv.y, xv.z, xv.w};
#pragma unroll
    for (int j = 0; j < 4; j++) {
      const float4* wr = (const float4*)&wg[(size_t)(d0 + i * 4 + j) * 8];
      float4 w0 = wr[0], w1v = wr[1];
      double xd = (double)xs[j];
      acc[0] += xd * (double)w0.x;  acc[1] += xd * (double)w0.y;
      acc[2] += xd * (double)w0.z;  acc[3] += xd * (double)w0.w;
      acc[4] += xd * (double)w1v.x; acc[5] += xd * (double)w1v.y;
      acc[6] += xd * (double)w1v.z; acc[7] += xd * (double)w1v.w;
    }
  }
#pragma unroll
  for (int off = 32; off; off >>= 1) {
#pragma unroll
    for (int e = 0; e < 8; e++) acc[e] += __shfl_down(acc[e], off);
  }
  if (lane == 0) {
    double m = acc[0];
    for (int e = 1; e < 8; e++) m = acc[e] > m ? acc[e] : m;
    double p[8]; double s = 0;
    for (int e = 0; e < 8; e++) { p[e] = exp(acc[e] - m); s += p[e]; }
    const double inv = 1.0 / s;
    for (int e = 0; e < 8; e++) {
      logits[(size_t)t * 8 + e] = (float)acc[e];
      probs [(size_t)t * 8 + e] = (float)(p[e] * inv);
    }
  }
}

// ---------- per-expert transpose + fp32->bf16: out[C][R] = in[R][C] ----------
__global__ void transpose_cvt_kernel(const float* __restrict__ in, unsigned short* __restrict__ out,
                                     const int R, const int C) {
  __shared__ float t[64][65];
  const int e = blockIdx.z;
  const float* inp = in + (size_t)e * R * C;
  unsigned short* outp = out + (size_t)e * R * C;
  const int r0 = blockIdx.y * 64, c0 = blockIdx.x * 64;
  const int tid = threadIdx.x;
  const int lr = tid >> 4;          // 0..15
  const int lc = (tid & 15) * 4;    // 0..60
#pragma unroll
  for (int i = 0; i < 4; i++) {
    const int r = lr + i * 16;
    const float4 v = *(const float4*)&inp[(size_t)(r0 + r) * C + c0 + lc];
    t[r][lc] = v.x; t[r][lc + 1] = v.y; t[r][lc + 2] = v.z; t[r][lc + 3] = v.w;
  }
  __syncthreads();
#pragma unroll
  for (int i = 0; i < 4; i++) {
    const int oc = lr + i * 16;     // output row (a C-index)
    union { ushort4 u4; unsigned short u[4]; } u;
#pragma unroll
    for (int j = 0; j < 4; j++) u.u[j] = f2bf(t[lc + j][oc]);
    *(ushort4*)&outp[(size_t)(c0 + oc) * R + r0 + lc] = u.u4;
  }
}

// ---------- expert-choice top-k: u32-key rank counting, 3-region loop ----------
__global__ void topk_kernel(const float* __restrict__ logits, const float* __restrict__ probs,
                            int* __restrict__ sel, float* __restrict__ gate) {
  __shared__ unsigned int keys[S_];
  const int idx = blockIdx.x;       // 0..127 : (b,e) x 8 segments
  const int seg = idx & 7;
  const int be = idx >> 3;          // 0..15
  const int b = be >> 3;            // 0..1
  const int e = be & 7;
  const int tid = threadIdx.x;
  // load + order-preserving float->u32 key transform (descending == key-descending)
  for (int i = tid; i < S_; i += 256) {
    unsigned int u = __float_as_uint(logits[((size_t)(b * S_ + i)) * E_ + e]);
    keys[i] = u ^ ((u & 0x80000000u) ? 0xFFFFFFFFu : 0x80000000u);
  }
  __syncthreads();
  const int s = seg * 256 + tid;          // this thread's candidate index
  const unsigned int vk = keys[s];
  const int wave = tid >> 6;
  const int W0 = seg * 256 + wave * 64;   // the wave's 64-candidate window
  int rank = 0;
  // region 1: i < W0  ->  i < s for every lane: tie counts  ->  kv >= vk
#pragma unroll 4
  for (int i = 0; i < W0; i += 4) {
    const uint4 kv = *(const uint4*)&keys[i];
    rank += (kv.x >= vk) + (kv.y >= vk) + (kv.z >= vk) + (kv.w >= vk);
  }
  // region 2: the window containing s: full lexicographic check
#pragma unroll
  for (int j = 0; j < 64; j++) {
    const int i = W0 + j;
    const unsigned int kv = keys[i];
    rank += (kv > vk) || (kv == vk && i < s);
  }
  // region 3: i >= W0+64  ->  i > s for every lane: tie doesn't count  ->  kv > vk
#pragma unroll 4
  for (int i = W0 + 64; i < S_; i += 4) {
    const uint4 kv = *(const uint4*)&keys[i];
    rank += (kv.x > vk) + (kv.y > vk) + (kv.z > vk) + (kv.w > vk);
  }
  if (rank < KCAP) {
    sel [e * ROWS + b * KCAP + rank] = b * S_ + s;
    gate[e * ROWS + b * KCAP + rank] = probs[((size_t)(b * S_ + s)) * E_ + e];
  }
}

// ====================== GEMM1: h = gelu(gather(x) . w1^T + b1) ======================
// 64x64x64 tiles, 2-phase dbuf prefetch, XOR-swizzled LDS, expert-per-XCD mapping.
__global__ __launch_bounds__(256, 4) void gemm1_kernel(
    const unsigned short* __restrict__ xb,   // [NTOK][D_]
    const unsigned short* __restrict__ w1t,  // [E][F_][D_]
    const float* __restrict__ b1,            // [E][F_]
    const int* __restrict__ sel,             // [E][ROWS]
    unsigned short* __restrict__ hbuf) {     // [E][ROWS][F_]
  __shared__ unsigned short As[2 * TILE_ELEMS];
  __shared__ unsigned short Bs[2 * TILE_ELEMS];
  // bijective XCD chunking: 2048 blocks = 8 XCDs x 256; XCD x owns expert x
  const int bid = blockIdx.x;
  const int lid = (bid & 7) * 256 + (bid >> 3);
  const int e   = lid >> 8;           // 0..7
  const int rem = lid & 255;
  const int n0  = (rem >> 3) * BN;    // 0..31 -> F panels
  const int m0  = (rem & 7) * BM;     // 0..7  -> row panels
  const int tid = threadIdx.x;
  const int wave = tid >> 6, lane = tid & 63;
  const int wr = wave >> 1, wc = wave & 1;

  // staging: per gload16 a wave covers 8 rows x 8 chunks of 16B.
  // LDS(r, c) = Global(r, c ^ (r&7))  -> pre-swizzle SOURCE chunk (rule 21).
  const int srow = lane >> 3;                 // 0..7 == r&7 (rowbase % 8 == 0)
  const int schunk = (lane & 7) ^ srow;
  const unsigned short* asrc[2];
  const unsigned short* bsrc[2];
#pragma unroll
  for (int j = 0; j < 2; j++) {
    const int r = wave * 16 + j * 8 + srow;
    const int tok = sel[e * ROWS + m0 + r];
    asrc[j] = xb + (size_t)tok * D_ + schunk * 8;
    bsrc[j] = w1t + ((size_t)e * F_ + n0 + r) * D_ + schunk * 8;
  }

  f32x4 acc[2][2];
#pragma unroll
  for (int mi = 0; mi < 2; mi++)
#pragma unroll
    for (int nj = 0; nj < 2; nj++) acc[mi][nj] = (f32x4){0.f, 0.f, 0.f, 0.f};

  const int fr = lane & 15;

  auto stage = [&](int buf, int k0) {
#pragma unroll
    for (int j = 0; j < 2; j++) {
      gload16(&As[buf * TILE_ELEMS + (wave * 16 + j * 8) * BK], asrc[j] + k0);
      gload16(&Bs[buf * TILE_ELEMS + (wave * 16 + j * 8) * BK], bsrc[j] + k0);
    }
  };
  auto compute = [&](int buf) {
    const unsigned short* Ab = &As[buf * TILE_ELEMS];
    const unsigned short* Bb = &Bs[buf * TILE_ELEMS];
    bf16x8 a[2][2], b[2][2];
#pragma unroll
    for (int kk = 0; kk < 2; kk++) {
      const int xch = ((kk * 4 + (lane >> 4)) ^ (lane & 7)) * 8;  // swizzled read chunk
#pragma unroll
      for (int mi = 0; mi < 2; mi++)
        a[kk][mi] = *(const bf16x8*)&Ab[(wr * 32 + mi * 16 + fr) * BK + xch];
#pragma unroll
      for (int nj = 0; nj < 2; nj++)
        b[kk][nj] = *(const bf16x8*)&Bb[(wc * 32 + nj * 16 + fr) * BK + xch];
    }
#pragma unroll
    for (int kk = 0; kk < 2; kk++)
#pragma unroll
      for (int mi = 0; mi < 2; mi++)
#pragma unroll
        for (int nj = 0; nj < 2; nj++)
          acc[mi][nj] = __builtin_amdgcn_mfma_f32_16x16x32_bf16(a[kk][mi], b[kk][nj], acc[mi][nj], 0, 0, 0);
  };

  stage(0, 0);
  __syncthreads();
  int cur = 0;
  for (int t = 0; t < D_ / BK - 1; t++) {
    stage(cur ^ 1, (t + 1) * BK);     // prefetch next tile, in flight under compute
    compute(cur);
    __syncthreads();                  // drains vmcnt(0): next tile ready
    cur ^= 1;
  }
  compute(cur);

  const int lr = (lane >> 4) * 4;
#pragma unroll
  for (int mi = 0; mi < 2; mi++)
#pragma unroll
    for (int nj = 0; nj < 2; nj++)
#pragma unroll
      for (int rg = 0; rg < 4; rg++) {
        const int row = m0 + wr * 32 + mi * 16 + lr + rg;
        const int col = n0 + wc * 32 + nj * 16 + fr;
        float v = acc[mi][nj][rg] + b1[e * F_ + col];
        v = 0.5f * v * (1.0f + erff(v * 0.70710678118654752f));   // exact GELU
        hbuf[((size_t)e * ROWS + row) * F_ + col] = f2bf(v);
      }
}

// ---------- row LayerNorm over F_, in place on bf16 h ----------
__global__ void ln_kernel(unsigned short* __restrict__ hbuf,
                          const float* __restrict__ g_ln, const float* __restrict__ b_ln) {
  const int row = blockIdx.x;          // 0..E_*ROWS-1
  const int e = row >> 9;
  unsigned short* hr = hbuf + (size_t)row * F_;
  const int tid = threadIdx.x;
  union { bf16x8 v; unsigned short u[8]; } u;
  u.v = *(const bf16x8*)&hr[tid * 8];
  float vals[8]; float s1 = 0.f, s2 = 0.f;
#pragma unroll
  for (int j = 0; j < 8; j++) { float f = bf2f(u.u[j]); vals[j] = f; s1 += f; s2 += f * f; }
#pragma unroll
  for (int off = 32; off; off >>= 1) { s1 += __shfl_down(s1, off); s2 += __shfl_down(s2, off); }
  __shared__ float rs[8];
  const int wave = tid >> 6, lane = tid & 63;
  if (lane == 0) { rs[wave] = s1; rs[wave + 4] = s2; }
  __syncthreads();
  const float t1 = rs[0] + rs[1] + rs[2] + rs[3];
  const float t2 = rs[4] + rs[5] + rs[6] + rs[7];
  const float mu = t1 * (1.f / F_);
  const float var = t2 * (1.f / F_) - mu * mu;   // biased var (jnp.var)
  const float rstd = rsqrtf(var + 1e-5f);
  const float4* gl4 = (const float4*)(g_ln + (size_t)e * F_ + tid * 8);
  const float4* bl4 = (const float4*)(b_ln + (size_t)e * F_ + tid * 8);
  float4 g0 = gl4[0], g1 = gl4[1], bb0 = bl4[0], bb1 = bl4[1];
  float gs[8] = {g0.x, g0.y, g0.z, g0.w, g1.x, g1.y, g1.z, g1.w};
  float bs[8] = {bb0.x, bb0.y, bb0.z, bb0.w, bb1.x, bb1.y, bb1.z, bb1.w};
  union { bf16x8 v; unsigned short u[8]; } o;
#pragma unroll
  for (int j = 0; j < 8; j++)
    o.u[j] = f2bf((vals[j] - mu) * rstd * gs[j] + bs[j]);
  *(bf16x8*)&hr[tid * 8] = o.v;
}

// ====================== GEMM2: out[tok] += gate * (h . w2^T + b2) ======================
__global__ __launch_bounds__(256, 4) void gemm2_kernel(
    const unsigned short* __restrict__ hbuf, // [E][ROWS][F_]
    const unsigned short* __restrict__ w2t,  // [E][O_][F_]
    const float* __restrict__ b2,            // [E][O_]
    const int* __restrict__ sel, const float* __restrict__ gate,
    float* __restrict__ out) {               // [NTOK][O_]
  __shared__ unsigned short As[2 * TILE_ELEMS];
  __shared__ unsigned short Bs[2 * TILE_ELEMS];
  // 1024 blocks = 8 XCDs x 128; XCD x owns expert x
  const int bid = blockIdx.x;
  const int lid = (bid & 7) * 128 + (bid >> 3);
  const int e   = lid >> 7;           // 0..7
  const int rem = lid & 127;
  const int n0  = (rem >> 3) * BN;    // 0..15 -> O panels
  const int m0  = (rem & 7) * BM;     // 0..7
  const int tid = threadIdx.x;
  const int wave = tid >> 6, lane = tid & 63;
  const int wr = wave >> 1, wc = wave & 1;

  const int srow = lane >> 3;
  const int schunk = (lane & 7) ^ srow;
  const unsigned short* asrc[2];
  const unsigned short* bsrc[2];
#pragma unroll
  for (int j = 0; j < 2; j++) {
    const int r = wave * 16 + j * 8 + srow;
    asrc[j] = hbuf + ((size_t)e * ROWS + m0 + r) * F_ + schunk * 8;
    bsrc[j] = w2t + ((size_t)e * O_ + n0 + r) * F_ + schunk * 8;
  }

  f32x4 acc[2][2];
#pragma unroll
  for (int mi = 0; mi < 2; mi++)
#pragma unroll
    for (int nj = 0; nj < 2; nj++) acc[mi][nj] = (f32x4){0.f, 0.f, 0.f, 0.f};

  const int fr = lane & 15;

  auto stage = [&](int buf, int k0) {
#pragma unroll
    for (int j = 0; j < 2; j++) {
      gload16(&As[buf * TILE_ELEMS + (wave * 16 + j * 8) * BK], asrc[j] + k0);
      gload16(&Bs[buf * TILE_ELEMS + (wave * 16 + j * 8) * BK], bsrc[j] + k0);
    }
  };
  auto compute = [&](int buf) {
    const unsigned short* Ab = &As[buf * TILE_ELEMS];
    const unsigned short* Bb = &Bs[buf * TILE_ELEMS];
    bf16x8 a[2][2], b[2][2];
#pragma unroll
    for (int kk = 0; kk < 2; kk++) {
      const int xch = ((kk * 4 + (lane >> 4)) ^ (lane & 7)) * 8;
#pragma unroll
      for (int mi = 0; mi < 2; mi++)
        a[kk][mi] = *(const bf16x8*)&Ab[(wr * 32 + mi * 16 + fr) * BK + xch];
#pragma unroll
      for (int nj = 0; nj < 2; nj++)
        b[kk][nj] = *(const bf16x8*)&Bb[(wc * 32 + nj * 16 + fr) * BK + xch];
    }
#pragma unroll
    for (int kk = 0; kk < 2; kk++)
#pragma unroll
      for (int mi = 0; mi < 2; mi++)
#pragma unroll
        for (int nj = 0; nj < 2; nj++)
          acc[mi][nj] = __builtin_amdgcn_mfma_f32_16x16x32_bf16(a[kk][mi], b[kk][nj], acc[mi][nj], 0, 0, 0);
  };

  stage(0, 0);
  __syncthreads();
  int cur = 0;
  for (int t = 0; t < F_ / BK - 1; t++) {
    stage(cur ^ 1, (t + 1) * BK);
    compute(cur);
    __syncthreads();
    cur ^= 1;
  }
  compute(cur);

  const int lr = (lane >> 4) * 4;
#pragma unroll
  for (int mi = 0; mi < 2; mi++) {
#pragma unroll
    for (int rg = 0; rg < 4; rg++) {
      const int row = m0 + wr * 32 + mi * 16 + lr + rg;
      const int tok = sel[e * ROWS + row];
      const float g = gate[e * ROWS + row];
#pragma unroll
      for (int nj = 0; nj < 2; nj++) {
        const int col = n0 + wc * 32 + nj * 16 + fr;
        const float v = acc[mi][nj][rg] + b2[e * O_ + col];
        atomicAdd(&out[(size_t)tok * O_ + col], g * v);
      }
    }
  }
}

// ---------- launch ----------
extern "C" void kernel_launch(void* const* d_in, const int* in_sizes, int n_in,
                              void* d_out, int out_size, void* d_ws, size_t ws_size,
                              hipStream_t stream) {
  const float* x     = (const float*)d_in[0];
  const float* wg    = (const float*)d_in[1];
  const float* w1    = (const float*)d_in[2];
  const float* b1    = (const float*)d_in[3];
  const float* g_ln  = (const float*)d_in[4];
  const float* b_ln  = (const float*)d_in[5];
  const float* w2    = (const float*)d_in[6];
  const float* b2    = (const float*)d_in[7];
  float* out = (float*)d_out;
  float* out_logits = out + (size_t)NTOK * O_;

  char* wsb = (char*)d_ws;
  unsigned short* xb   = (unsigned short*)(wsb + 0);          // 8,388,608 B
  unsigned short* w1t  = (unsigned short*)(wsb + 8388608);    // 33,554,432 B
  unsigned short* w2t  = (unsigned short*)(wsb + 41943040);   // 33,554,432 B
  unsigned short* hbuf = (unsigned short*)(wsb + 75497472);   // 16,777,216 B
  float* probs = (float*)(wsb + 92274688);                    // 131,072 B
  int*   sel   = (int*)  (wsb + 92405760);                    // 16,384 B
  float* gate  = (float*)(wsb + 92422144);                    // 16,384 B

  // zero the moe-output region (atomic accumulation target)
  hipMemsetAsync(d_out, 0, (size_t)NTOK * O_ * sizeof(float), stream);

  gating_kernel<<<NTOK / 4, 256, 0, stream>>>(x, wg, out_logits, probs, xb);
  transpose_cvt_kernel<<<dim3(F_ / 64, D_ / 64, E_), 256, 0, stream>>>(w1, w1t, D_, F_); // -> [F][D]
  transpose_cvt_kernel<<<dim3(O_ / 64, F_ / 64, E_), 256, 0, stream>>>(w2, w2t, F_, O_); // -> [O][F]
  topk_kernel<<<2 * E_ * 8, 256, 0, stream>>>(out_logits, probs, sel, gate);
  gemm1_kernel<<<(F_ / BN) * (ROWS / BM) * E_, 256, 0, stream>>>(xb, w1t, b1, sel, hbuf);
  ln_kernel<<<E_ * ROWS, 256, 0, stream>>>(hbuf, g_ln, b_ln);
  gemm2_kernel<<<(O_ / BN) * (ROWS / BM) * E_, 256, 0, stream>>>(hbuf, w2t, b2, sel, gate, out);
}